// Round 8
// baseline (91.674 us; speedup 1.0000x reference)
//
#include <hip/hip_runtime.h>
#include <math.h>

#define N1 16384
#define N2 16384
#define BLOCK 512                      // phase-1 block: 8 waves (R6-validated)
#define PTS 4                          // pos1 points per thread
#define I_BLOCKS (N1 / (BLOCK * PTS))  // 8 columns
#define SLICES 64                      // pos2 slices -> grid 8x64 = 512 blocks
#define SLICE_F4 ((N2 / SLICES) / 2)   // 128 float4 per slice (512 B... 2 KB)
#define FBLOCK 256                     // finish block (proven R0 shape)

// R7 post-mortem: instr count (R2), occupancy (R6), atomic count/contention
// (R7) ALL null -> nn_partial is near its ~10 us VALU floor; remaining slack
// is dispatch count + end-of-kernel atomic drain. This round removes both:
// per-slice minima go to DISJOINT partials[sl][i] (no init -> the 64 KB
// memset dispatch disappears; no atomics -> no coherent-point drain at
// kernel end). Cross-XCD visibility of plain stores is guaranteed at the
// dispatch boundary (R1 proved this handoff: absmax 0.0).
//
// Stage 1: for each pos1 point, min over one pos2 slice of
//   g(q) = -2 p.q + |q|^2   (d^2 = |p|^2 + g, shift applied in stage 2),
//   pos1 pre-scaled by -2 (exact). Inner: 2 fma + v_min3. Coalesced stores.
__global__ __launch_bounds__(BLOCK, 8)
void nn_partial(const float2* __restrict__ pos1,
                const float4* __restrict__ pos2,   // 2 points per float4
                float* __restrict__ partials,      // [SLICES][N1], no init
                unsigned int* __restrict__ ticket) {
    const int ib = blockIdx.x;
    const int sl = blockIdx.y;
    const int t  = threadIdx.x;

    if (ib == 0 && sl == 0 && t == 0) *ticket = 0;  // for stage-2 election
    const float4* __restrict__ q = pos2 + (size_t)sl * SLICE_F4;
    const int i0 = ib * (BLOCK * PTS) + t;

    float x[PTS], y[PTS], m[PTS];
#pragma unroll
    for (int k = 0; k < PTS; ++k) {
        float2 p = pos1[i0 + k * BLOCK];
        x[k] = -2.f * p.x;   // fold -2 into p (exact)
        y[k] = -2.f * p.y;
        m[k] = 3.4e38f;
    }

#pragma unroll 4
    for (int j = 0; j < SLICE_F4; ++j) {
        float4 qq = q[j];                          // uniform address, 2 pos2 pts
        float az = fmaf(qq.x, qq.x, qq.y * qq.y);  // |qa|^2
        float bz = fmaf(qq.z, qq.z, qq.w * qq.w);  // |qb|^2
#pragma unroll
        for (int k = 0; k < PTS; ++k) {
            float ta = fmaf(x[k], qq.x, fmaf(y[k], qq.y, az));
            float tb = fmaf(x[k], qq.z, fmaf(y[k], qq.w, bz));
            m[k] = fminf(m[k], fminf(ta, tb));     // -> v_min3_f32
        }
    }

    float* dst = partials + (size_t)sl * N1 + i0;
#pragma unroll
    for (int k = 0; k < PTS; ++k) {
        dst[k * BLOCK] = m[k];                     // coalesced, fire-and-forget
    }
}

// Stage 2: 64 blocks; min across the 64 slice-partials (coalesced, L2/L3-hot,
// exact under any association), + |p|^2, sqrt, block-sum; last block (ticket)
// reduces the 64 block sums and writes the mean. Proven R0 tail.
__global__ __launch_bounds__(FBLOCK)
void nn_finish(const float* __restrict__ partials,
               const float2* __restrict__ pos1,
               float* __restrict__ blocksums,
               unsigned int* __restrict__ ticket,
               float* __restrict__ out) {
    const int t = threadIdx.x;
    const int i = blockIdx.x * FBLOCK + t;

    float g = 3.4e38f;
#pragma unroll 8
    for (int sl = 0; sl < SLICES; ++sl) {
        g = fminf(g, partials[(size_t)sl * N1 + i]);
    }

    float2 p = pos1[i];
    float d2 = fmaxf(fmaf(p.x, p.x, p.y * p.y) + g, 0.f);
    float sum = sqrtf(d2);

    for (int off = 32; off > 0; off >>= 1) {
        sum += __shfl_down(sum, off, 64);
    }
    __shared__ float wsum[FBLOCK / 64];
    __shared__ int lastflag;
    if ((t & 63) == 0) wsum[t >> 6] = sum;
    __syncthreads();
    if (t == 0) {
        float s = 0.f;
        for (int w = 0; w < FBLOCK / 64; ++w) s += wsum[w];
        blocksums[blockIdx.x] = s;
        __threadfence();
        unsigned int old = atomicAdd(ticket, 1u);
        lastflag = (old == gridDim.x - 1) ? 1 : 0;
    }
    __syncthreads();
    if (lastflag && t < 64) {
        volatile float* vb = (volatile float*)blocksums;
        float v = vb[t];
        for (int off = 32; off > 0; off >>= 1) {
            v += __shfl_down(v, off, 64);
        }
        if (t == 0) out[0] = v / (float)N1;
    }
}

extern "C" void kernel_launch(void* const* d_in, const int* in_sizes, int n_in,
                              void* d_out, int out_size, void* d_ws, size_t ws_size,
                              hipStream_t stream) {
    const float2* pos1 = (const float2*)d_in[0];
    const float4* pos2 = (const float4*)d_in[1];
    float* out = (float*)d_out;

    float* partials      = (float*)d_ws;                    // [64][16384] = 4 MB
    float* blocksums     = partials + (size_t)SLICES * N1;  // 64 floats
    unsigned int* ticket = (unsigned int*)(blocksums + 64); // 1 uint

    dim3 grid1(I_BLOCKS, SLICES);
    nn_partial<<<grid1, BLOCK, 0, stream>>>(pos1, pos2, partials, ticket);
    nn_finish<<<N1 / FBLOCK, FBLOCK, 0, stream>>>(partials, pos1, blocksums,
                                                  ticket, out);
}